// Round 6
// baseline (164.375 us; speedup 1.0000x reference)
//
#include <hip/hip_runtime.h>
#include <cstdint>

// ---------------------------------------------------------------------------
// GRUCell w/ BatchNorm on input projection.  B=4096, I=H=1024, 3H=3072.
// Reference:  c = tanh(c_bn + (r * hx) @ c_h)  (Python left-assoc * then @).
// fp16 scheme (mfma_f32_16x16x32_f16, fp32 accum):
//   GEMM1: g  = input @ wi          1-pass, 128x64 tiles, 1536 blocks
//   GEMM2: gh = hx @ wh[:, :2H]     2-pass (B split hi+lo), 128x64, 1024 blks
//   GEMM3: ch = rx @ wh[:, 2H:]     1-pass, 64x64 tiles, 1024 blocks
// Round-5 lesson: 128x128 tiles left GEMM2/3 grid-starved (2 blocks/CU,
// Occupancy 21%, MfmaUtil 18%) -> latency-bound.  Narrow tiles restore TLP.
// Fused epilogues: GEMM1 -> g fp16 + BN partials; GEMM2 -> u + rx; GEMM3 -> hy.
// ---------------------------------------------------------------------------

typedef float    f4    __attribute__((ext_vector_type(4)));
typedef _Float16 half4 __attribute__((ext_vector_type(4)));
typedef _Float16 half8 __attribute__((ext_vector_type(8)));
typedef float    f32x4 __attribute__((ext_vector_type(4)));

__device__ __forceinline__ float sigm(float x) { return 1.f / (1.f + __expf(-x)); }
__device__ __forceinline__ float tanh_sat(float t) {
  return 1.f - 2.f / (__expf(2.f * t) + 1.f);   // saturates correctly for big t
}

// --------------------------- prep kernels ----------------------------------

__global__ void convert2(const float* __restrict__ a, const float* __restrict__ b,
                         _Float16* __restrict__ da, _Float16* __restrict__ db,
                         int n4each) {
  int i = blockIdx.x * blockDim.x + threadIdx.x;
  const float* s;
  _Float16* d;
  if (i < n4each) { s = a; d = da; }
  else            { s = b; d = db; i -= n4each; }
  f4 v = ((const f4*)s)[i];
  half4 h;
#pragma unroll
  for (int j = 0; j < 4; ++j) h[j] = (_Float16)v[j];
  ((half4*)d)[i] = h;
}

// wi -> WiT (no split), wh -> WhTh/WhTl (split), one dispatch (blockIdx.z)
__global__ void transpose2(const float* __restrict__ wi, const float* __restrict__ wh,
                           _Float16* __restrict__ WiT, _Float16* __restrict__ WhTh,
                           _Float16* __restrict__ WhTl, int K, int N) {
  __shared__ float sh[32][33];
  const bool split = blockIdx.z != 0;
  const float* W = split ? wh : wi;
  int n0 = blockIdx.x * 32, k0 = blockIdx.y * 32;
  int tx = threadIdx.x & 31, ty = threadIdx.x >> 5;  // ty 0..7
#pragma unroll
  for (int i = 0; i < 4; ++i) {
    int k = ty + i * 8;
    sh[k][tx] = W[(size_t)(k0 + k) * N + n0 + tx];
  }
  __syncthreads();
#pragma unroll
  for (int i = 0; i < 4; ++i) {
    int nn = ty + i * 8;
    float v = sh[tx][nn];                      // = W[k0+tx][n0+nn]
    size_t o = (size_t)(n0 + nn) * K + k0 + tx;
    _Float16 h = (_Float16)v;
    if (!split) {
      WiT[o] = h;
    } else {
      WhTh[o] = h;
      WhTl[o] = (_Float16)(v - (float)h);
    }
  }
}

// ------------------------------- GEMM ---------------------------------------
// BMt x BNt tile, BK=64, 4 waves (2x2); wave = (BMt/2) x (BNt/2); frags of
// mfma_f32_16x16x32_f16.  A row-major fp16 [M][1024]; B pre-transposed
// Bt[N][1024] fp16 (hi [+lo if SPLIT]).  LDS [rows][8 slots of 8 fp16],
// slot stored at slot^(row&7) (same fn on write & read -> conflict-free b128).
// K-loop: barrier; store(kt); barrier; issue load(kt+1); compute(kt).

#define BK 64

template <int EPI, bool SPLIT, int BMt, int BNt>
__global__ __launch_bounds__(256, 4) void gemm16(
    const _Float16* __restrict__ A, const _Float16* __restrict__ Bh,
    const _Float16* __restrict__ Bl, _Float16* __restrict__ g16,
    const float* __restrict__ scale, const float* __restrict__ shift,
    const _Float16* __restrict__ hxf, _Float16* __restrict__ ubuf,
    _Float16* __restrict__ rxbuf, float* __restrict__ out,
    float* __restrict__ psum, float* __restrict__ psq) {
  constexpr int K  = 1024;
  constexpr int NT = K / BK;                    // 16
  constexpr int TA = BMt * BK;
  constexpr int TB = BNt * BK;
  constexpr int MF    = BMt / 32;               // m-frags per wave
  constexpr int WCOLS = BNt / 32;               // n-frags per wave
  constexpr int ACH = TA / 2048;                // 16B chunks per thread (A)
  constexpr int BCH = TB / 2048;                // 16B chunks per thread (B)
  __shared__ _Float16 lds[TA + TB * (SPLIT ? 2 : 1)];

  const int tid  = threadIdx.x;
  const int lane = tid & 63;
  const int wid  = tid >> 6;

  // XCD-aware bijective remap (gridDim.x % 8 == 0): XCD owns a column panel
  int flat = blockIdx.y * gridDim.x + blockIdx.x;
  int cpx  = gridDim.x >> 3;
  int xcd  = flat & 7, idx = flat >> 3;
  int bx   = xcd * cpx + idx / gridDim.y;
  int by   = idx % gridDim.y;

  const int brow = by * BMt;
  const int bcol = bx * BNt;
  const int wrow = (wid >> 1) * (BMt / 2);
  const int wcol = (wid & 1) * (BNt / 2);

  half8 rA[ACH], rBh[BCH], rBl[BCH];

  auto load_tile = [&](int kt) {
    const int k0 = kt * BK;
#pragma unroll
    for (int i = 0; i < ACH; ++i) {
      int c = i * 256 + tid, row = c >> 3, slot = c & 7;
      rA[i] = *(const half8*)(A + (size_t)(brow + row) * K + k0 + slot * 8);
    }
#pragma unroll
    for (int i = 0; i < BCH; ++i) {
      int c = i * 256 + tid, row = c >> 3, slot = c & 7;
      size_t o = (size_t)(bcol + row) * K + k0 + slot * 8;
      rBh[i] = *(const half8*)(Bh + o);
      if constexpr (SPLIT) rBl[i] = *(const half8*)(Bl + o);
    }
  };
  auto store_tile = [&]() {
#pragma unroll
    for (int i = 0; i < ACH; ++i) {
      int c = i * 256 + tid, row = c >> 3, slot = c & 7;
      int off = row * 64 + ((slot ^ (row & 7)) << 3);
      *(half8*)(lds + off) = rA[i];
    }
#pragma unroll
    for (int i = 0; i < BCH; ++i) {
      int c = i * 256 + tid, row = c >> 3, slot = c & 7;
      int off = row * 64 + ((slot ^ (row & 7)) << 3);
      *(half8*)(lds + TA + off) = rBh[i];
      if constexpr (SPLIT) *(half8*)(lds + TA + TB + off) = rBl[i];
    }
  };

  f32x4 acc[MF][WCOLS];
#pragma unroll
  for (int i = 0; i < MF; ++i)
#pragma unroll
    for (int j = 0; j < WCOLS; ++j) acc[i][j] = f32x4{0.f, 0.f, 0.f, 0.f};

  load_tile(0);
  for (int kt = 0; kt < NT; ++kt) {
    __syncthreads();                  // prev tile's LDS reads done
    store_tile();
    __syncthreads();                  // staged data visible
    if (kt + 1 < NT) load_tile(kt + 1);   // hide under compute below

#pragma unroll
    for (int h = 0; h < 2; ++h) {
      half8 a[MF], bh[WCOLS], bl[WCOLS];
      const int kg = h * 4 + (lane >> 4);
#pragma unroll
      for (int m = 0; m < MF; ++m) {
        int r = wrow + m * 16 + (lane & 15);
        a[m] = *(const half8*)(lds + r * 64 + ((kg ^ (r & 7)) << 3));
      }
#pragma unroll
      for (int n = 0; n < WCOLS; ++n) {
        int r = wcol + n * 16 + (lane & 15);
        int off = TA + r * 64 + ((kg ^ (r & 7)) << 3);
        bh[n] = *(const half8*)(lds + off);
        if constexpr (SPLIT) bl[n] = *(const half8*)(lds + TB + off);
      }
#pragma unroll
      for (int m = 0; m < MF; ++m)
#pragma unroll
        for (int n = 0; n < WCOLS; ++n) {
          acc[m][n] = __builtin_amdgcn_mfma_f32_16x16x32_f16(
              a[m], bh[n], acc[m][n], 0, 0, 0);
          if constexpr (SPLIT)
            acc[m][n] = __builtin_amdgcn_mfma_f32_16x16x32_f16(
                a[m], bl[n], acc[m][n], 0, 0, 0);
        }
    }
  }

  // ---- epilogues.  D(row,col): col = lane&15, row = (lane>>4)*4 + j.
  if constexpr (EPI == 0) {           // g (fp16) + BN column partial sums
    float s[WCOLS], q[WCOLS];
#pragma unroll
    for (int n = 0; n < WCOLS; ++n) { s[n] = 0.f; q[n] = 0.f; }
#pragma unroll
    for (int m = 0; m < MF; ++m) {
      int row = brow + wrow + m * 16 + (lane >> 4) * 4;
#pragma unroll
      for (int n = 0; n < WCOLS; ++n) {
        int gcol = bcol + wcol + n * 16 + (lane & 15);
#pragma unroll
        for (int j = 0; j < 4; ++j) {
          float v = acc[m][n][j];
          g16[(size_t)(row + j) * 3072 + gcol] = (_Float16)v;
          s[n] += v;
          q[n] += v * v;
        }
      }
    }
#pragma unroll
    for (int n = 0; n < WCOLS; ++n) {
      float sv = s[n], qv = q[n];
      sv += __shfl_xor(sv, 16); sv += __shfl_xor(sv, 32);
      qv += __shfl_xor(qv, 16); qv += __shfl_xor(qv, 32);
      if (lane < 16) {
        int prow = by * 2 + (wid >> 1);          // 64 partial rows (BMt=128)
        int pcol = bcol + wcol + n * 16 + lane;
        psum[(size_t)prow * 3072 + pcol] = sv;
        psq [(size_t)prow * 3072 + pcol] = qv;
      }
    }
  } else if constexpr (EPI == 1) {    // u gate (fp16) + rx = r*hx (fp16)
#pragma unroll
    for (int m = 0; m < MF; ++m) {
      int row0 = brow + wrow + m * 16 + (lane >> 4) * 4;
#pragma unroll
      for (int n = 0; n < WCOLS; ++n) {
        int gcol = bcol + wcol + n * 16 + (lane & 15);   // 0..2047
        float sc = scale[gcol], sf = shift[gcol];
#pragma unroll
        for (int j = 0; j < 4; ++j) {
          int row = row0 + j;
          float pre = (float)g16[(size_t)row * 3072 + gcol] * sc + sf
                      + acc[m][n][j];
          if (gcol < 1024) {
            ubuf[(size_t)row * 1024 + gcol] = (_Float16)sigm(pre);
          } else {
            int hc = gcol - 1024;
            float r = sigm(pre);
            rxbuf[(size_t)row * 1024 + hc] =
                (_Float16)(r * (float)hxf[(size_t)row * 1024 + hc]);
          }
        }
      }
    }
  } else {                            // EPI == 2: hy = hx + u*(c - hx)
#pragma unroll
    for (int m = 0; m < MF; ++m) {
      int row0 = brow + wrow + m * 16 + (lane >> 4) * 4;
#pragma unroll
      for (int n = 0; n < WCOLS; ++n) {
        int lcol = bcol + wcol + n * 16 + (lane & 15);   // 0..1023
        int gcol = 2048 + lcol;
        float sc = scale[gcol], sf = shift[gcol];
#pragma unroll
        for (int j = 0; j < 4; ++j) {
          int row = row0 + j;
          float t = (float)g16[(size_t)row * 3072 + gcol] * sc + sf
                    + acc[m][n][j];
          float c = tanh_sat(t);
          float u = (float)ubuf[(size_t)row * 1024 + lcol];
          float x = (float)hxf[(size_t)row * 1024 + lcol];
          out[(size_t)row * 1024 + lcol] = x + u * (c - x);
        }
      }
    }
  }
}

// --------------------------- BN final ---------------------------------------

__global__ void bn_final(const float* __restrict__ psum, const float* __restrict__ psq,
                         const float* __restrict__ gamma, const float* __restrict__ beta,
                         const float* __restrict__ bias, float* __restrict__ scale,
                         float* __restrict__ shift, int nparts, int Ncols, float invM) {
  int col = blockIdx.x * blockDim.x + threadIdx.x;
  if (col >= Ncols) return;
  float s = 0.f, q = 0.f;
  for (int i = 0; i < nparts; ++i) {
    s += psum[(size_t)i * Ncols + col];
    q += psq [(size_t)i * Ncols + col];
  }
  float m   = s * invM;
  float var = q * invM - m * m;
  float r   = rsqrtf(var + 1e-5f);
  float sc  = r * gamma[col];
  scale[col] = sc;
  shift[col] = beta[col] + bias[col] - m * sc;
}

// ------------------------------ launch ---------------------------------------

extern "C" void kernel_launch(void* const* d_in, const int* in_sizes, int n_in,
                              void* d_out, int out_size, void* d_ws, size_t ws_size,
                              hipStream_t stream) {
  const float* input = (const float*)d_in[0];   // 4096x1024
  const float* hx    = (const float*)d_in[1];   // 4096x1024
  const float* wi    = (const float*)d_in[2];   // 1024x3072
  const float* wh    = (const float*)d_in[3];   // 1024x3072
  const float* bias  = (const float*)d_in[4];   // 3072
  const float* gamma = (const float*)d_in[5];   // 3072
  const float* beta  = (const float*)d_in[6];   // 3072
  float* out = (float*)d_out;

  const int B = 4096, I = 1024, N3 = 3072;

  char* ws = (char*)d_ws;
  _Float16* g16   = (_Float16*)(ws);               // 24 MiB [4096][3072] fp16
  _Float16* ubuf  = (_Float16*)(ws + 25165824);    // 8 MiB
  _Float16* Xf16  = (_Float16*)(ws + 33554432);    // 8 MiB
  _Float16* Hf16  = (_Float16*)(ws + 41943040);    // 8 MiB
  _Float16* RXf16 = (_Float16*)(ws + 50331648);    // 8 MiB
  _Float16* WiT   = (_Float16*)(ws + 58720256);    // 6 MiB
  _Float16* WhTh  = (_Float16*)(ws + 65011712);    // 6 MiB
  _Float16* WhTl  = (_Float16*)(ws + 71303168);    // 6 MiB
  float*    psum  = (float*)   (ws + 77594624);    // 768 KiB [64][3072]
  float*    psq   = (float*)   (ws + 78381056);    // 768 KiB
  float*    scale = (float*)   (ws + 79167488);    // 12 KiB
  float*    shift = (float*)   (ws + 79179776);    // 12 KiB

  // ---- prep (2 dispatches)
  convert2<<<8192, 256, 0, stream>>>(input, hx, Xf16, Hf16, B * I / 4);
  transpose2<<<dim3(96, 32, 2), 256, 0, stream>>>(wi, wh, WiT, WhTh, WhTl, I, N3);

  // ---- GEMM1 (1-pass, 128x64): g = input @ wi -> g16 + BN partials
  gemm16<0, false, 128, 64><<<dim3(48, 32), 256, 0, stream>>>(
      Xf16, WiT, nullptr, g16, nullptr, nullptr, nullptr, nullptr, nullptr,
      nullptr, psum, psq);

  // ---- BN fold
  bn_final<<<12, 256, 0, stream>>>(psum, psq, gamma, beta, bias,
                                   scale, shift, 64, N3, 1.f / (float)B);

  // ---- GEMM2 (2-pass, 128x64): hx @ wh[:, :2048] -> u (fp16), rx (fp16)
  gemm16<1, true, 128, 64><<<dim3(32, 32), 256, 0, stream>>>(
      Hf16, WhTh, WhTl, g16, scale, shift, Hf16, ubuf, RXf16,
      nullptr, nullptr, nullptr);

  // ---- GEMM3 (1-pass, 64x64): rx @ wh[:, 2048:] -> hy
  gemm16<2, false, 64, 64><<<dim3(16, 64), 256, 0, stream>>>(
      RXf16, WhTh + (size_t)2048 * 1024, nullptr, g16,
      scale, shift, Hf16, ubuf, nullptr, out, nullptr, nullptr);
}

// Round 7
// 155.797 us; speedup vs baseline: 1.0551x; 1.0551x over previous
//
#include <hip/hip_runtime.h>
#include <cstdint>

// ---------------------------------------------------------------------------
// GRUCell w/ BatchNorm on input projection.  B=4096, I=H=1024, 3H=3072.
// Reference:  c = tanh(c_bn + (r * hx) @ c_h)  (Python left-assoc * then @).
// fp16 scheme (mfma_f32_16x16x32_f16, fp32 accum):
//   GEMM1: g  = input @ wi         1-pass, 128x128, 768 blocks (3/CU)
//   GEMM2: gh = hx @ wh[:, :2H]    u-cols 1-pass, r-cols 2-pass, 128x64 (4/CU)
//   GEMM3: ch = rx @ wh[:, 2H:]    1-pass, 64x64 (4/CU)
// Round-7: global_load_lds staging (linear LDS dest + inverse-swizzled global
// source + swizzled ds_read; rule both-sides-or-neither).  Round-6's
// reg-staging exposed load latency in-wave every k-step (MfmaUtil 23%).
// Fused epilogues: GEMM1 -> g fp16 + BN partials; GEMM2 -> u + rx; GEMM3 -> hy.
// ---------------------------------------------------------------------------

typedef float    f4    __attribute__((ext_vector_type(4)));
typedef _Float16 half4 __attribute__((ext_vector_type(4)));
typedef _Float16 half8 __attribute__((ext_vector_type(8)));
typedef float    f32x4 __attribute__((ext_vector_type(4)));

__device__ __forceinline__ float sigm(float x) { return 1.f / (1.f + __expf(-x)); }
__device__ __forceinline__ float tanh_sat(float t) {
  return 1.f - 2.f / (__expf(2.f * t) + 1.f);   // saturates correctly for big t
}

// async global->LDS DMA, 16B/lane: LDS dst = wave-uniform base + lane*16
__device__ __forceinline__ void gload16(const _Float16* g, _Float16* l) {
  __builtin_amdgcn_global_load_lds(
      (const __attribute__((address_space(1))) void*)g,
      (__attribute__((address_space(3))) void*)l, 16, 0, 0);
}

// --------------------------- prep kernels ----------------------------------

__global__ void convert2(const float* __restrict__ a, const float* __restrict__ b,
                         _Float16* __restrict__ da, _Float16* __restrict__ db,
                         int n4each) {
  int i = blockIdx.x * blockDim.x + threadIdx.x;
  const float* s;
  _Float16* d;
  if (i < n4each) { s = a; d = da; }
  else            { s = b; d = db; i -= n4each; }
  f4 v = ((const f4*)s)[i];
  half4 h;
#pragma unroll
  for (int j = 0; j < 4; ++j) h[j] = (_Float16)v[j];
  ((half4*)d)[i] = h;
}

// wi -> WiT (no split), wh -> WhTh/WhTl (split), one dispatch (blockIdx.z)
__global__ void transpose2(const float* __restrict__ wi, const float* __restrict__ wh,
                           _Float16* __restrict__ WiT, _Float16* __restrict__ WhTh,
                           _Float16* __restrict__ WhTl, int K, int N) {
  __shared__ float sh[32][33];
  const bool split = blockIdx.z != 0;
  const float* W = split ? wh : wi;
  int n0 = blockIdx.x * 32, k0 = blockIdx.y * 32;
  int tx = threadIdx.x & 31, ty = threadIdx.x >> 5;  // ty 0..7
#pragma unroll
  for (int i = 0; i < 4; ++i) {
    int k = ty + i * 8;
    sh[k][tx] = W[(size_t)(k0 + k) * N + n0 + tx];
  }
  __syncthreads();
#pragma unroll
  for (int i = 0; i < 4; ++i) {
    int nn = ty + i * 8;
    float v = sh[tx][nn];                      // = W[k0+tx][n0+nn]
    size_t o = (size_t)(n0 + nn) * K + k0 + tx;
    _Float16 h = (_Float16)v;
    if (!split) {
      WiT[o] = h;
    } else {
      WhTh[o] = h;
      WhTl[o] = (_Float16)(v - (float)h);
    }
  }
}

// ------------------------------- GEMM ---------------------------------------
// BMt x BNt tile, BK=64, 4 waves (2x2); wave = (BMt/2) x (BNt/2); frags of
// mfma_f32_16x16x32_f16.  A row-major fp16 [M][1024]; B pre-transposed
// Bt[N][1024] fp16.  LDS tile [rows][8 slots of 8 fp16]; linear position
// (row, slot) holds global k-group (slot ^ (row&7)) -- achieved by swizzling
// the per-lane GLOBAL source of global_load_lds (dest stays linear), and the
// same XOR on ds_read.  K-loop: barrier; stage-DMA(kt); barrier (compiler
// drains vmcnt(0)); compute(kt).  Other resident blocks hide the DMA wait.
// BSPL: 0 = 1-pass, 1 = 2-pass (B hi+lo), 2 = gate-split (bcol>=1024 2-pass).

#define BK 64

template <int EPI, int BSPL, int BMt, int BNt>
__global__ __launch_bounds__(256, 3) void gemm16(
    const _Float16* __restrict__ A, const _Float16* __restrict__ Bh,
    const _Float16* __restrict__ Bl, _Float16* __restrict__ g16,
    const float* __restrict__ scale, const float* __restrict__ shift,
    const _Float16* __restrict__ hxf, _Float16* __restrict__ ubuf,
    _Float16* __restrict__ rxbuf, float* __restrict__ out,
    float* __restrict__ psum, float* __restrict__ psq) {
  constexpr int K  = 1024;
  constexpr int NT = K / BK;                    // 16
  constexpr int TA = BMt * BK;
  constexpr int TB = BNt * BK;
  constexpr int MF = BMt / 32;                  // m-frags per wave
  constexpr int WC = BNt / 32;                  // n-frags per wave
  constexpr int ACH = BMt / 8;                  // 1KB chunks in A tile
  constexpr int BCH = BNt / 8;                  // 1KB chunks in B tile
  __shared__ _Float16 lds[TA + TB * (BSPL ? 2 : 1)];

  const int tid  = threadIdx.x;
  const int lane = tid & 63;
  const int wid  = tid >> 6;

  // XCD-aware bijective remap (gridDim.x % 8 == 0): XCD owns a column panel
  int flat = blockIdx.y * gridDim.x + blockIdx.x;
  int cpx  = gridDim.x >> 3;
  int xcd  = flat & 7, idx = flat >> 3;
  int bx   = xcd * cpx + idx / gridDim.y;
  int by   = idx % gridDim.y;

  const int brow = by * BMt;
  const int bcol = bx * BNt;
  const int wrow = (wid >> 1) * (BMt / 2);
  const int wcol = (wid & 1) * (BNt / 2);

  const bool use_lo = (BSPL == 1) || (BSPL == 2 && bcol >= 1024);
  const int nchunks = ACH + BCH + (use_lo ? BCH : 0);

  // staging geometry: chunk = 1KB = 8 rows x 8 slots; lane l lands at LDS
  // linear (row = c*8 + (l>>3), slot = l&7); source k-group = (l&7)^(l>>3).
  const int srow = lane >> 3;
  const int sko  = (((lane & 7) ^ srow) << 3);

  f32x4 acc[MF][WC];
#pragma unroll
  for (int i = 0; i < MF; ++i)
#pragma unroll
    for (int j = 0; j < WC; ++j) acc[i][j] = f32x4{0.f, 0.f, 0.f, 0.f};

  for (int kt = 0; kt < NT; ++kt) {
    const int k0 = kt * BK;
    __syncthreads();                  // all waves done reading prev tile
    for (int c = wid; c < nchunks; c += 4) {
      if (c < ACH) {
        gload16(A + (size_t)(brow + c * 8 + srow) * K + k0 + sko,
                lds + c * 512);
      } else if (c < ACH + BCH) {
        int bc = c - ACH;
        gload16(Bh + (size_t)(bcol + bc * 8 + srow) * K + k0 + sko,
                lds + TA + bc * 512);
      } else {
        int bc = c - ACH - BCH;
        gload16(Bl + (size_t)(bcol + bc * 8 + srow) * K + k0 + sko,
                lds + TA + TB + bc * 512);
      }
    }
    __syncthreads();                  // compiler drains vmcnt(0) -> LDS valid

#pragma unroll
    for (int h = 0; h < 2; ++h) {
      half8 a[MF], bhv[WC], blv[WC];
      const int kg = h * 4 + (lane >> 4);
#pragma unroll
      for (int m = 0; m < MF; ++m) {
        int r = wrow + m * 16 + (lane & 15);
        a[m] = *(const half8*)(lds + r * 64 + ((kg ^ (r & 7)) << 3));
      }
#pragma unroll
      for (int n = 0; n < WC; ++n) {
        int r = wcol + n * 16 + (lane & 15);
        int off = TA + r * 64 + ((kg ^ (r & 7)) << 3);
        bhv[n] = *(const half8*)(lds + off);
        if (BSPL && use_lo) blv[n] = *(const half8*)(lds + TB + off);
      }
#pragma unroll
      for (int m = 0; m < MF; ++m)
#pragma unroll
        for (int n = 0; n < WC; ++n) {
          acc[m][n] = __builtin_amdgcn_mfma_f32_16x16x32_f16(
              a[m], bhv[n], acc[m][n], 0, 0, 0);
          if (BSPL && use_lo)
            acc[m][n] = __builtin_amdgcn_mfma_f32_16x16x32_f16(
                a[m], blv[n], acc[m][n], 0, 0, 0);
        }
    }
  }

  // ---- epilogues.  D(row,col): col = lane&15, row = (lane>>4)*4 + j.
  if constexpr (EPI == 0) {           // g (fp16) + BN column partial sums
    float s[WC], q[WC];
#pragma unroll
    for (int n = 0; n < WC; ++n) { s[n] = 0.f; q[n] = 0.f; }
#pragma unroll
    for (int m = 0; m < MF; ++m) {
      int row = brow + wrow + m * 16 + (lane >> 4) * 4;
#pragma unroll
      for (int n = 0; n < WC; ++n) {
        int gcol = bcol + wcol + n * 16 + (lane & 15);
#pragma unroll
        for (int j = 0; j < 4; ++j) {
          float v = acc[m][n][j];
          g16[(size_t)(row + j) * 3072 + gcol] = (_Float16)v;
          s[n] += v;
          q[n] += v * v;
        }
      }
    }
#pragma unroll
    for (int n = 0; n < WC; ++n) {
      float sv = s[n], qv = q[n];
      sv += __shfl_xor(sv, 16); sv += __shfl_xor(sv, 32);
      qv += __shfl_xor(qv, 16); qv += __shfl_xor(qv, 32);
      if (lane < 16) {
        int prow = by * 2 + (wid >> 1);          // 64 partial rows (BMt=128)
        int pcol = bcol + wcol + n * 16 + lane;
        psum[(size_t)prow * 3072 + pcol] = sv;
        psq [(size_t)prow * 3072 + pcol] = qv;
      }
    }
  } else if constexpr (EPI == 1) {    // u gate (fp16) + rx = r*hx (fp16)
#pragma unroll
    for (int m = 0; m < MF; ++m) {
      int row0 = brow + wrow + m * 16 + (lane >> 4) * 4;
#pragma unroll
      for (int n = 0; n < WC; ++n) {
        int gcol = bcol + wcol + n * 16 + (lane & 15);   // 0..2047
        float sc = scale[gcol], sf = shift[gcol];
#pragma unroll
        for (int j = 0; j < 4; ++j) {
          int row = row0 + j;
          float pre = (float)g16[(size_t)row * 3072 + gcol] * sc + sf
                      + acc[m][n][j];
          if (gcol < 1024) {
            ubuf[(size_t)row * 1024 + gcol] = (_Float16)sigm(pre);
          } else {
            int hc = gcol - 1024;
            float r = sigm(pre);
            rxbuf[(size_t)row * 1024 + hc] =
                (_Float16)(r * (float)hxf[(size_t)row * 1024 + hc]);
          }
        }
      }
    }
  } else {                            // EPI == 2: hy = hx + u*(c - hx)
#pragma unroll
    for (int m = 0; m < MF; ++m) {
      int row0 = brow + wrow + m * 16 + (lane >> 4) * 4;
#pragma unroll
      for (int n = 0; n < WC; ++n) {
        int lcol = bcol + wcol + n * 16 + (lane & 15);   // 0..1023
        int gcol = 2048 + lcol;
        float sc = scale[gcol], sf = shift[gcol];
#pragma unroll
        for (int j = 0; j < 4; ++j) {
          int row = row0 + j;
          float t = (float)g16[(size_t)row * 3072 + gcol] * sc + sf
                    + acc[m][n][j];
          float c = tanh_sat(t);
          float u = (float)ubuf[(size_t)row * 1024 + lcol];
          float x = (float)hxf[(size_t)row * 1024 + lcol];
          out[(size_t)row * 1024 + lcol] = x + u * (c - x);
        }
      }
    }
  }
}

// --------------------------- BN final ---------------------------------------

__global__ void bn_final(const float* __restrict__ psum, const float* __restrict__ psq,
                         const float* __restrict__ gamma, const float* __restrict__ beta,
                         const float* __restrict__ bias, float* __restrict__ scale,
                         float* __restrict__ shift, int nparts, int Ncols, float invM) {
  int col = blockIdx.x * blockDim.x + threadIdx.x;
  if (col >= Ncols) return;
  float s = 0.f, q = 0.f;
  for (int i = 0; i < nparts; ++i) {
    s += psum[(size_t)i * Ncols + col];
    q += psq [(size_t)i * Ncols + col];
  }
  float m   = s * invM;
  float var = q * invM - m * m;
  float r   = rsqrtf(var + 1e-5f);
  float sc  = r * gamma[col];
  scale[col] = sc;
  shift[col] = beta[col] + bias[col] - m * sc;
}

// ------------------------------ launch ---------------------------------------

extern "C" void kernel_launch(void* const* d_in, const int* in_sizes, int n_in,
                              void* d_out, int out_size, void* d_ws, size_t ws_size,
                              hipStream_t stream) {
  const float* input = (const float*)d_in[0];   // 4096x1024
  const float* hx    = (const float*)d_in[1];   // 4096x1024
  const float* wi    = (const float*)d_in[2];   // 1024x3072
  const float* wh    = (const float*)d_in[3];   // 1024x3072
  const float* bias  = (const float*)d_in[4];   // 3072
  const float* gamma = (const float*)d_in[5];   // 3072
  const float* beta  = (const float*)d_in[6];   // 3072
  float* out = (float*)d_out;

  const int B = 4096, I = 1024, N3 = 3072;

  char* ws = (char*)d_ws;
  _Float16* g16   = (_Float16*)(ws);               // 24 MiB [4096][3072] fp16
  _Float16* ubuf  = (_Float16*)(ws + 25165824);    // 8 MiB
  _Float16* Xf16  = (_Float16*)(ws + 33554432);    // 8 MiB
  _Float16* Hf16  = (_Float16*)(ws + 41943040);    // 8 MiB
  _Float16* RXf16 = (_Float16*)(ws + 50331648);    // 8 MiB
  _Float16* WiT   = (_Float16*)(ws + 58720256);    // 6 MiB
  _Float16* WhTh  = (_Float16*)(ws + 65011712);    // 6 MiB
  _Float16* WhTl  = (_Float16*)(ws + 71303168);    // 6 MiB
  float*    psum  = (float*)   (ws + 77594624);    // 768 KiB [64][3072]
  float*    psq   = (float*)   (ws + 78381056);    // 768 KiB
  float*    scale = (float*)   (ws + 79167488);    // 12 KiB
  float*    shift = (float*)   (ws + 79179776);    // 12 KiB

  // ---- prep (2 dispatches)
  convert2<<<8192, 256, 0, stream>>>(input, hx, Xf16, Hf16, B * I / 4);
  transpose2<<<dim3(96, 32, 2), 256, 0, stream>>>(wi, wh, WiT, WhTh, WhTl, I, N3);

  // ---- GEMM1 (1-pass, 128x128, 3 blocks/CU): g = input @ wi -> g16 + partials
  gemm16<0, 0, 128, 128><<<dim3(24, 32), 256, 0, stream>>>(
      Xf16, WiT, nullptr, g16, nullptr, nullptr, nullptr, nullptr, nullptr,
      nullptr, psum, psq);

  // ---- BN fold
  bn_final<<<12, 256, 0, stream>>>(psum, psq, gamma, beta, bias,
                                   scale, shift, 64, N3, 1.f / (float)B);

  // ---- GEMM2 (gate-split passes, 128x64, 4 blocks/CU): -> u (fp16), rx (fp16)
  gemm16<1, 2, 128, 64><<<dim3(32, 32), 256, 0, stream>>>(
      Hf16, WhTh, WhTl, g16, scale, shift, Hf16, ubuf, RXf16,
      nullptr, nullptr, nullptr);

  // ---- GEMM3 (1-pass, 64x64, 4 blocks/CU): rx @ wh[:, 2048:] -> hy
  gemm16<2, 0, 64, 64><<<dim3(16, 64), 256, 0, stream>>>(
      RXf16, WhTh + (size_t)2048 * 1024, nullptr, g16,
      scale, shift, Hf16, ubuf, nullptr, out, nullptr, nullptr);
}

// Round 8
// 146.405 us; speedup vs baseline: 1.1227x; 1.0642x over previous
//
#include <hip/hip_runtime.h>
#include <cstdint>

// ---------------------------------------------------------------------------
// GRUCell w/ BatchNorm on input projection.  B=4096, I=H=1024, 3H=3072.
// Reference:  c = tanh(c_bn + (r * hx) @ c_h)  (Python left-assoc * then @).
// fp16 scheme (mfma_f32_16x16x32_f16, fp32 accum):
//   MEGA : [g | gh_raw] = [input@wi (3072c, 1-pass) | hx@wh_u (1024c, 1-pass)
//          | hx@wh_r (1024c, 2-pass B hi+lo)]   -- one 5120-col dispatch,
//          2560 blocks (round-7: two grid-starved dispatches at 4 blk/CU,
//          MfmaUtil 15%; and runtime pass-branch inside the MFMA loop).
//   bn_final -> scale/shift;  rx = sigmoid(BN(g_r)+gh_r)*hx  (fp16)
//   GEMM3: ch = rx @ wh_c (1-pass); epilogue computes u from raw gh_u -> hy.
// ---------------------------------------------------------------------------

typedef float    f4    __attribute__((ext_vector_type(4)));
typedef _Float16 half4 __attribute__((ext_vector_type(4)));
typedef _Float16 half8 __attribute__((ext_vector_type(8)));
typedef float    f32x4 __attribute__((ext_vector_type(4)));

__device__ __forceinline__ float sigm(float x) { return 1.f / (1.f + __expf(-x)); }
__device__ __forceinline__ float tanh_sat(float t) {
  return 1.f - 2.f / (__expf(2.f * t) + 1.f);   // saturates correctly for big t
}

// async global->LDS DMA, 16B/lane: LDS dst = wave-uniform base + lane*16
__device__ __forceinline__ void gload16(const _Float16* g, _Float16* l) {
  __builtin_amdgcn_global_load_lds(
      (const __attribute__((address_space(1))) void*)g,
      (__attribute__((address_space(3))) void*)l, 16, 0, 0);
}

// --------------------------- prep kernels ----------------------------------

__global__ void convert2(const float* __restrict__ a, const float* __restrict__ b,
                         _Float16* __restrict__ da, _Float16* __restrict__ db,
                         int n4each) {
  int i = blockIdx.x * blockDim.x + threadIdx.x;
  const float* s;
  _Float16* d;
  if (i < n4each) { s = a; d = da; }
  else            { s = b; d = db; i -= n4each; }
  f4 v = ((const f4*)s)[i];
  half4 h;
#pragma unroll
  for (int j = 0; j < 4; ++j) h[j] = (_Float16)v[j];
  ((half4*)d)[i] = h;
}

// wi -> WiT; wh -> WhTh (+ WhTl only for r-cols 1024..2047); one dispatch
__global__ void transpose2(const float* __restrict__ wi, const float* __restrict__ wh,
                           _Float16* __restrict__ WiT, _Float16* __restrict__ WhTh,
                           _Float16* __restrict__ WhTl, int K, int N) {
  __shared__ float sh[32][33];
  const bool iswh = blockIdx.z != 0;
  const float* W = iswh ? wh : wi;
  int n0 = blockIdx.x * 32, k0 = blockIdx.y * 32;
  int tx = threadIdx.x & 31, ty = threadIdx.x >> 5;  // ty 0..7
#pragma unroll
  for (int i = 0; i < 4; ++i) {
    int k = ty + i * 8;
    sh[k][tx] = W[(size_t)(k0 + k) * N + n0 + tx];
  }
  __syncthreads();
  const bool wlo = iswh && n0 >= 1024 && n0 < 2048;   // r-cols need lo part
#pragma unroll
  for (int i = 0; i < 4; ++i) {
    int nn = ty + i * 8;
    float v = sh[tx][nn];                      // = W[k0+tx][n0+nn]
    size_t o = (size_t)(n0 + nn) * K + k0 + tx;
    _Float16 h = (_Float16)v;
    if (!iswh) {
      WiT[o] = h;
    } else {
      WhTh[o] = h;
      if (wlo) WhTl[o] = (_Float16)(v - (float)h);
    }
  }
}

// ------------------------------- GEMM core ----------------------------------
// BMt x BNt tile, BK=64, 4 waves (2x2); A pre-offset to brow, row-major fp16
// [.][1024]; B pre-transposed [BNt rows][1024] fp16.  LDS [rows][8 slots of
// 8 fp16]; linear slot holds k-group (slot ^ (row&7)): inverse-swizzled
// global source for global_load_lds (dest linear) + same XOR on ds_read.
// K-loop: barrier; stage-DMA(kt); barrier; compute(kt).  Cross-block wave
// overlap (5+ blocks/CU) hides the vmcnt(0) drain.

template <bool LO, int BMt, int BNt>
__device__ __forceinline__ void kloop(
    const _Float16* __restrict__ A, const _Float16* __restrict__ Bh,
    const _Float16* __restrict__ Bl, _Float16* lds, int tid,
    f32x4 (&acc)[BMt / 32][BNt / 32]) {
  constexpr int TA = BMt * 64, TB = BNt * 64;
  constexpr int MF = BMt / 32, WC = BNt / 32;
  const int lane = tid & 63, wid = tid >> 6;
  const int srow = lane >> 3;                       // row within 8-row chunk
  const int sko  = (((lane & 7) ^ srow) << 3);      // inverse-swizzled k-group
  const int wrow = (wid >> 1) * (BMt / 2);
  const int wcol = (wid & 1) * (BNt / 2);

  for (int kt = 0; kt < 16; ++kt) {
    const int k0 = kt * 64;
    __syncthreads();                  // all waves done reading prev tile
#pragma unroll
    for (int i = 0; i < MF; ++i) {    // A chunks: BMt/8 total, MF per wave
      int c = wid * MF + i;
      gload16(A + (size_t)(c * 8 + srow) * 1024 + k0 + sko, lds + c * 512);
    }
#pragma unroll
    for (int i = 0; i < WC; ++i) {    // B chunks: BNt/8 total, WC per wave
      int c = wid * WC + i;
      size_t go = (size_t)(c * 8 + srow) * 1024 + k0 + sko;
      gload16(Bh + go, lds + TA + c * 512);
      if constexpr (LO) gload16(Bl + go, lds + TA + TB + c * 512);
    }
    __syncthreads();                  // drains vmcnt(0) -> LDS valid

#pragma unroll
    for (int h = 0; h < 2; ++h) {
      half8 a[MF], bhv[WC], blv[WC];
      const int kg = h * 4 + (lane >> 4);
#pragma unroll
      for (int m = 0; m < MF; ++m) {
        int r = wrow + m * 16 + (lane & 15);
        a[m] = *(const half8*)(lds + r * 64 + ((kg ^ (r & 7)) << 3));
      }
#pragma unroll
      for (int n = 0; n < WC; ++n) {
        int r = wcol + n * 16 + (lane & 15);
        int off = TA + r * 64 + ((kg ^ (r & 7)) << 3);
        bhv[n] = *(const half8*)(lds + off);
        if constexpr (LO) blv[n] = *(const half8*)(lds + TB + off);
      }
#pragma unroll
      for (int m = 0; m < MF; ++m)
#pragma unroll
        for (int n = 0; n < WC; ++n) {
          acc[m][n] = __builtin_amdgcn_mfma_f32_16x16x32_f16(
              a[m], bhv[n], acc[m][n], 0, 0, 0);
          if constexpr (LO)
            acc[m][n] = __builtin_amdgcn_mfma_f32_16x16x32_f16(
                a[m], blv[n], acc[m][n], 0, 0, 0);
        }
    }
  }
}

// ---- MEGA: 5120 output cols = [g 0..3071 | gh_u 3072..4095 | gh_r 4096..5119]
__global__ __launch_bounds__(256, 4) void gemm_mega(
    const _Float16* __restrict__ Xf16, const _Float16* __restrict__ Hf16,
    const _Float16* __restrict__ WiT, const _Float16* __restrict__ WhTh,
    const _Float16* __restrict__ WhTl, _Float16* __restrict__ g16,
    _Float16* __restrict__ ghbuf, float* __restrict__ psum,
    float* __restrict__ psq) {
  __shared__ _Float16 lds[128 * 64 + 2 * 64 * 64];   // 32 KiB

  const int tid  = threadIdx.x;
  const int lane = tid & 63;
  const int wid  = tid >> 6;

  // XCD-aware bijective remap (gridDim.x = 80, %8 == 0)
  int flat = blockIdx.y * gridDim.x + blockIdx.x;
  int cpx  = gridDim.x >> 3;                         // 10
  int xcd  = flat & 7, idx = flat >> 3;
  int bx   = xcd * cpx + idx / gridDim.y;
  int by   = idx % gridDim.y;

  const int brow = by * 128;
  const int bcol = bx * 64;                          // 0..5119
  const bool is_g = bcol < 3072;
  const bool lo   = bcol >= 4096;
  const int wrow = (wid >> 1) * 64;
  const int wcol = (wid & 1) * 32;

  const _Float16* Ap = (is_g ? Xf16 : Hf16) + (size_t)brow * 1024;
  const _Float16* Bp = is_g ? WiT + (size_t)bcol * 1024
                            : WhTh + (size_t)(bcol - 3072) * 1024;
  const _Float16* Blp = WhTl + (size_t)(lo ? bcol - 3072 : 0) * 1024;

  f32x4 acc[4][2];
#pragma unroll
  for (int i = 0; i < 4; ++i)
#pragma unroll
    for (int j = 0; j < 2; ++j) acc[i][j] = f32x4{0.f, 0.f, 0.f, 0.f};

  if (lo) kloop<true, 128, 64>(Ap, Bp, Blp, lds, tid, acc);
  else    kloop<false, 128, 64>(Ap, Bp, nullptr, lds, tid, acc);

  // D(row,col): col = lane&15, row = (lane>>4)*4 + j
  if (is_g) {                         // g (fp16) + BN column partial sums
    float s[2] = {0.f, 0.f}, q[2] = {0.f, 0.f};
#pragma unroll
    for (int m = 0; m < 4; ++m) {
      int row = brow + wrow + m * 16 + (lane >> 4) * 4;
#pragma unroll
      for (int n = 0; n < 2; ++n) {
        int gcol = bcol + wcol + n * 16 + (lane & 15);
#pragma unroll
        for (int j = 0; j < 4; ++j) {
          float v = acc[m][n][j];
          g16[(size_t)(row + j) * 3072 + gcol] = (_Float16)v;
          s[n] += v;
          q[n] += v * v;
        }
      }
    }
#pragma unroll
    for (int n = 0; n < 2; ++n) {
      float sv = s[n], qv = q[n];
      sv += __shfl_xor(sv, 16); sv += __shfl_xor(sv, 32);
      qv += __shfl_xor(qv, 16); qv += __shfl_xor(qv, 32);
      if (lane < 16) {
        int prow = by * 2 + (wid >> 1);              // 64 partial rows
        int pcol = bcol + wcol + n * 16 + lane;
        psum[(size_t)prow * 3072 + pcol] = sv;
        psq [(size_t)prow * 3072 + pcol] = qv;
      }
    }
  } else {                            // raw gh (fp16), ghbuf stride 2048
    int gh0 = bcol - 3072;
#pragma unroll
    for (int m = 0; m < 4; ++m) {
      int row = brow + wrow + m * 16 + (lane >> 4) * 4;
#pragma unroll
      for (int n = 0; n < 2; ++n) {
        int gcol = gh0 + wcol + n * 16 + (lane & 15);
#pragma unroll
        for (int j = 0; j < 4; ++j)
          ghbuf[(size_t)(row + j) * 2048 + gcol] = (_Float16)acc[m][n][j];
      }
    }
  }
}

// ---- GEMM3: ch = rx @ wh_c; epilogue computes u (from raw gh_u) and hy
__global__ __launch_bounds__(256, 4) void gemm_last(
    const _Float16* __restrict__ RXf16, const _Float16* __restrict__ Bc,
    const _Float16* __restrict__ g16, const _Float16* __restrict__ ghbuf,
    const _Float16* __restrict__ Hf16, const float* __restrict__ scale,
    const float* __restrict__ shift, float* __restrict__ out) {
  __shared__ _Float16 lds[64 * 64 + 64 * 64];        // 16 KiB

  const int tid  = threadIdx.x;
  const int lane = tid & 63;
  const int wid  = tid >> 6;

  int flat = blockIdx.y * gridDim.x + blockIdx.x;    // gridDim = (16,64)
  int cpx  = gridDim.x >> 3;                         // 2
  int xcd  = flat & 7, idx = flat >> 3;
  int bx   = xcd * cpx + idx / gridDim.y;
  int by   = idx % gridDim.y;

  const int brow = by * 64;
  const int bcol = bx * 64;                          // 0..1023
  const int wrow = (wid >> 1) * 32;
  const int wcol = (wid & 1) * 32;

  f32x4 acc[2][2];
#pragma unroll
  for (int i = 0; i < 2; ++i)
#pragma unroll
    for (int j = 0; j < 2; ++j) acc[i][j] = f32x4{0.f, 0.f, 0.f, 0.f};

  kloop<false, 64, 64>(RXf16 + (size_t)brow * 1024, Bc + (size_t)bcol * 1024,
                       nullptr, lds, tid, acc);

#pragma unroll
  for (int m = 0; m < 2; ++m) {
    int row0 = brow + wrow + m * 16 + (lane >> 4) * 4;
#pragma unroll
    for (int n = 0; n < 2; ++n) {
      int lcol = bcol + wcol + n * 16 + (lane & 15);
      float sc_u = scale[lcol],        sf_u = shift[lcol];
      float sc_c = scale[2048 + lcol], sf_c = shift[2048 + lcol];
#pragma unroll
      for (int j = 0; j < 4; ++j) {
        int row = row0 + j;
        float gu = (float)g16[(size_t)row * 3072 + lcol];
        float hu = (float)ghbuf[(size_t)row * 2048 + lcol];
        float u  = sigm(gu * sc_u + sf_u + hu);
        float gc = (float)g16[(size_t)row * 3072 + 2048 + lcol];
        float c  = tanh_sat(gc * sc_c + sf_c + acc[m][n][j]);
        float x  = (float)Hf16[(size_t)row * 1024 + lcol];
        out[(size_t)row * 1024 + lcol] = x + u * (c - x);
      }
    }
  }
}

// --------------------------- BN final ---------------------------------------

__global__ void bn_final(const float* __restrict__ psum, const float* __restrict__ psq,
                         const float* __restrict__ gamma, const float* __restrict__ beta,
                         const float* __restrict__ bias, float* __restrict__ scale,
                         float* __restrict__ shift, int nparts, int Ncols, float invM) {
  int col = blockIdx.x * blockDim.x + threadIdx.x;
  if (col >= Ncols) return;
  float s = 0.f, q = 0.f;
  for (int i = 0; i < nparts; ++i) {
    s += psum[(size_t)i * Ncols + col];
    q += psq [(size_t)i * Ncols + col];
  }
  float m   = s * invM;
  float var = q * invM - m * m;
  float r   = rsqrtf(var + 1e-5f);
  float sc  = r * gamma[col];
  scale[col] = sc;
  shift[col] = beta[col] + bias[col] - m * sc;
}

// --------------------- rx = sigmoid(BN(g_r)+gh_r) * hx ----------------------

__global__ void rx_split(const _Float16* __restrict__ g16,
                         const _Float16* __restrict__ ghbuf,
                         const _Float16* __restrict__ Hf16,
                         const float* __restrict__ scale,
                         const float* __restrict__ shift,
                         _Float16* __restrict__ rx) {
  int idx = blockIdx.x * blockDim.x + threadIdx.x;   // 4096*256
  int row = idx >> 8;
  int cv  = idx & 255;
  half4 gr = ((const half4*)g16)[(size_t)row * 768 + 256 + cv];   // g cols 1024+
  half4 hr = ((const half4*)ghbuf)[(size_t)row * 512 + 256 + cv]; // gh cols 1024+
  half4 xv = ((const half4*)Hf16)[(size_t)row * 256 + cv];
  int col = 1024 + cv * 4;
  f4 sr = *(const f4*)&scale[col];
  f4 fr = *(const f4*)&shift[col];
  half4 o;
#pragma unroll
  for (int j = 0; j < 4; ++j) {
    float r = sigm((float)gr[j] * sr[j] + fr[j] + (float)hr[j]);
    o[j] = (_Float16)(r * (float)xv[j]);
  }
  ((half4*)rx)[(size_t)row * 256 + cv] = o;
}

// ------------------------------ launch ---------------------------------------

extern "C" void kernel_launch(void* const* d_in, const int* in_sizes, int n_in,
                              void* d_out, int out_size, void* d_ws, size_t ws_size,
                              hipStream_t stream) {
  const float* input = (const float*)d_in[0];   // 4096x1024
  const float* hx    = (const float*)d_in[1];   // 4096x1024
  const float* wi    = (const float*)d_in[2];   // 1024x3072
  const float* wh    = (const float*)d_in[3];   // 1024x3072
  const float* bias  = (const float*)d_in[4];   // 3072
  const float* gamma = (const float*)d_in[5];   // 3072
  const float* beta  = (const float*)d_in[6];   // 3072
  float* out = (float*)d_out;

  const int B = 4096, I = 1024, N3 = 3072;

  char* ws = (char*)d_ws;
  _Float16* g16   = (_Float16*)(ws);               // 24 MiB [4096][3072]
  _Float16* ghbuf = (_Float16*)(ws + 25165824);    // 16 MiB [4096][2048] raw
  _Float16* Xf16  = (_Float16*)(ws + 41943040);    // 8 MiB
  _Float16* Hf16  = (_Float16*)(ws + 50331648);    // 8 MiB
  _Float16* RXf16 = (_Float16*)(ws + 58720256);    // 8 MiB
  _Float16* WiT   = (_Float16*)(ws + 67108864);    // 6 MiB
  _Float16* WhTh  = (_Float16*)(ws + 73400320);    // 6 MiB
  _Float16* WhTl  = (_Float16*)(ws + 79691776);    // 6 MiB (r-cols only)
  float*    psum  = (float*)   (ws + 85983232);    // 768 KiB [64][3072]
  float*    psq   = (float*)   (ws + 86769664);    // 768 KiB
  float*    scale = (float*)   (ws + 87556096);    // 12 KiB
  float*    shift = (float*)   (ws + 87568384);    // 12 KiB

  // ---- prep
  convert2<<<8192, 256, 0, stream>>>(input, hx, Xf16, Hf16, B * I / 4);
  transpose2<<<dim3(96, 32, 2), 256, 0, stream>>>(wi, wh, WiT, WhTh, WhTl, I, N3);

  // ---- MEGA GEMM: [g | gh_raw], 2560 blocks
  gemm_mega<<<dim3(80, 32), 256, 0, stream>>>(
      Xf16, Hf16, WiT, WhTh, WhTl, g16, ghbuf, psum, psq);

  // ---- BN fold
  bn_final<<<12, 256, 0, stream>>>(psum, psq, gamma, beta, bias,
                                   scale, shift, 64, N3, 1.f / (float)B);

  // ---- rx = sigmoid(BN(g_r) + gh_r) * hx
  rx_split<<<4096, 256, 0, stream>>>(g16, ghbuf, Hf16, scale, shift, RXf16);

  // ---- GEMM3 + fused u/c/hy epilogue
  gemm_last<<<dim3(16, 64), 256, 0, stream>>>(
      RXf16, WhTh + (size_t)2048 * 1024, g16, ghbuf, Hf16, scale, shift, out);
}

// Round 10
// 122.934 us; speedup vs baseline: 1.3371x; 1.1909x over previous
//
#include <hip/hip_runtime.h>
#include <cstdint>

// ---------------------------------------------------------------------------
// GRUCell w/ BatchNorm on input projection.  B=4096, I=H=1024, 3H=3072.
// Reference:  c = tanh(c_bn + (r * hx) @ c_h)  (Python left-assoc * then @).
// fp16 scheme (mfma_f32_16x16x32_f16, fp32 accum):
//   MEGA (one dispatch, two compile-time phases, both 32KB LDS / 32 MFMA per
//   wave per k-step):
//     blocks 0..1023 : 128x128 1-pass over [g(3072c) | gh_u(1024c)]
//     blocks 1024..1535: 128x64 2-pass (B hi+lo) over gh_r(1024c)
//   bn_final -> scale/shift;  rx = sigmoid(BN(g_r)+gh_r)*hx  (fp16)
//   GEMM3: ch = rx @ wh_c (1-pass, 64x64); epilogue computes u + hy.
// Round-9 bug: prep_all convert guard used 1048576/4 instead of 1048576
// (float4 count of a 4096x1024 array) -> OOB -> abort.  Fixed here.
// ---------------------------------------------------------------------------

typedef float    f4    __attribute__((ext_vector_type(4)));
typedef _Float16 half4 __attribute__((ext_vector_type(4)));
typedef _Float16 half8 __attribute__((ext_vector_type(8)));
typedef float    f32x4 __attribute__((ext_vector_type(4)));

__device__ __forceinline__ float sigm(float x) { return 1.f / (1.f + __expf(-x)); }
__device__ __forceinline__ float tanh_sat(float t) {
  return 1.f - 2.f / (__expf(2.f * t) + 1.f);   // saturates correctly for big t
}

// async global->LDS DMA, 16B/lane: LDS dst = wave-uniform base + lane*16
__device__ __forceinline__ void gload16(const _Float16* g, _Float16* l) {
  __builtin_amdgcn_global_load_lds(
      (const __attribute__((address_space(1))) void*)g,
      (__attribute__((address_space(3))) void*)l, 16, 0, 0);
}

// --------------------------- prep (one dispatch) ----------------------------
// bid < 8192: f32->fp16 convert of input+hx (x4 vectorized; 2*1048576 float4s).
// bid >= 8192: 32x32 transpose tiles; z=0 -> wi->WiT; z=1 -> wh->WhTh(+lo r).

__global__ void prep_all(const float* __restrict__ input, const float* __restrict__ hx,
                         const float* __restrict__ wi, const float* __restrict__ wh,
                         _Float16* __restrict__ Xf16, _Float16* __restrict__ Hf16,
                         _Float16* __restrict__ WiT, _Float16* __restrict__ WhTh,
                         _Float16* __restrict__ WhTl) {
  constexpr int N4 = 4096 * 1024 / 4;   // float4s per input array = 1048576
  __shared__ float sh[32][33];
  int bid = blockIdx.x;
  if (bid < 8192) {                     // 8192*256 = 2*N4 threads exactly
    int i = bid * 256 + threadIdx.x;
    const float* s;
    _Float16* d;
    if (i < N4) { s = input; d = Xf16; }
    else        { s = hx;    d = Hf16; i -= N4; }
    f4 v = ((const f4*)s)[i];
    half4 h;
#pragma unroll
    for (int j = 0; j < 4; ++j) h[j] = (_Float16)v[j];
    ((half4*)d)[i] = h;
    return;
  }
  int b2 = bid - 8192;                  // 0..6143: [z][ky 0..31][nx 0..95]
  int z = b2 / 3072; b2 %= 3072;
  int nx = b2 % 96, ky = b2 / 96;
  const float* W = z ? wh : wi;
  int n0 = nx * 32, k0 = ky * 32;
  int tx = threadIdx.x & 31, ty = threadIdx.x >> 5;  // ty 0..7
#pragma unroll
  for (int i = 0; i < 4; ++i) {
    int k = ty + i * 8;
    sh[k][tx] = W[(size_t)(k0 + k) * 3072 + n0 + tx];
  }
  __syncthreads();
  const bool wlo = z && n0 >= 1024 && n0 < 2048;     // r-cols need lo part
#pragma unroll
  for (int i = 0; i < 4; ++i) {
    int nn = ty + i * 8;
    float v = sh[tx][nn];                      // = W[k0+tx][n0+nn]
    size_t o = (size_t)(n0 + nn) * 1024 + k0 + tx;
    _Float16 h = (_Float16)v;
    if (!z) {
      WiT[o] = h;
    } else {
      WhTh[o] = h;
      if (wlo) WhTl[o] = (_Float16)(v - (float)h);
    }
  }
}

// ------------------------------- GEMM core ----------------------------------
// BMt x BNt tile, BK=64, 4 waves (2x2).  LDS [rows][8 slots of 8 fp16];
// linear slot holds k-group (slot ^ (row&7)): inverse-swizzled global source
// for global_load_lds (dest linear) + same XOR on ds_read.
// K-loop: barrier; stage-DMA(kt); barrier; compute(kt).

template <bool LO, int BMt, int BNt>
__device__ __forceinline__ void kloop(
    const _Float16* __restrict__ A, const _Float16* __restrict__ Bh,
    const _Float16* __restrict__ Bl, _Float16* lds, int tid,
    f32x4 (&acc)[BMt / 32][BNt / 32]) {
  constexpr int TA = BMt * 64, TB = BNt * 64;
  constexpr int MF = BMt / 32, WC = BNt / 32;
  const int lane = tid & 63, wid = tid >> 6;
  const int srow = lane >> 3;                       // row within 8-row chunk
  const int sko  = (((lane & 7) ^ srow) << 3);      // inverse-swizzled k-group
  const int wrow = (wid >> 1) * (BMt / 2);
  const int wcol = (wid & 1) * (BNt / 2);

  for (int kt = 0; kt < 16; ++kt) {
    const int k0 = kt * 64;
    __syncthreads();                  // all waves done reading prev tile
#pragma unroll
    for (int i = 0; i < MF; ++i) {    // A chunks: BMt/8 total, MF per wave
      int c = wid * MF + i;
      gload16(A + (size_t)(c * 8 + srow) * 1024 + k0 + sko, lds + c * 512);
    }
#pragma unroll
    for (int i = 0; i < WC; ++i) {    // B chunks: BNt/8 total, WC per wave
      int c = wid * WC + i;
      size_t go = (size_t)(c * 8 + srow) * 1024 + k0 + sko;
      gload16(Bh + go, lds + TA + c * 512);
      if constexpr (LO) gload16(Bl + go, lds + TA + TB + c * 512);
    }
    __syncthreads();                  // drains vmcnt(0) -> LDS valid

#pragma unroll
    for (int h = 0; h < 2; ++h) {
      half8 a[MF], bhv[WC], blv[WC];
      const int kg = h * 4 + (lane >> 4);
#pragma unroll
      for (int m = 0; m < MF; ++m) {
        int r = wrow + m * 16 + (lane & 15);
        a[m] = *(const half8*)(lds + r * 64 + ((kg ^ (r & 7)) << 3));
      }
#pragma unroll
      for (int n = 0; n < WC; ++n) {
        int r = wcol + n * 16 + (lane & 15);
        int off = TA + r * 64 + ((kg ^ (r & 7)) << 3);
        bhv[n] = *(const half8*)(lds + off);
        if constexpr (LO) blv[n] = *(const half8*)(lds + TB + off);
      }
#pragma unroll
      for (int m = 0; m < MF; ++m)
#pragma unroll
        for (int n = 0; n < WC; ++n) {
          acc[m][n] = __builtin_amdgcn_mfma_f32_16x16x32_f16(
              a[m], bhv[n], acc[m][n], 0, 0, 0);
          if constexpr (LO)
            acc[m][n] = __builtin_amdgcn_mfma_f32_16x16x32_f16(
                a[m], blv[n], acc[m][n], 0, 0, 0);
        }
    }
  }
}

// ---- MEGA: 1536 blocks.  0..1023: 128x128 1-pass over [g | gh_u] (4096c).
//                          1024..1535: 128x64 2-pass over gh_r (1024c).
__global__ __launch_bounds__(256, 4) void gemm_mega(
    const _Float16* __restrict__ Xf16, const _Float16* __restrict__ Hf16,
    const _Float16* __restrict__ WiT, const _Float16* __restrict__ WhTh,
    const _Float16* __restrict__ WhTl, _Float16* __restrict__ g16,
    _Float16* __restrict__ ghbuf, float* __restrict__ psum,
    float* __restrict__ psq) {
  __shared__ _Float16 lds[16384];                    // 32 KiB both phases

  const int tid  = threadIdx.x;
  const int lane = tid & 63;
  const int wid  = tid >> 6;
  const int bid  = blockIdx.x;

  if (bid < 1024) {
    // ---- phase 1: 128x128, 1-pass.  XCD owns 4 col-panels; rows sweep fast.
    int w  = (bid & 7) * 128 + (bid >> 3);
    int bx = w >> 5, by = w & 31;
    const int brow = by * 128;
    const int bcol = bx * 128;                       // 0..4095
    const bool is_g = bcol < 3072;
    const int wrow = (wid >> 1) * 64;
    const int wcol = (wid & 1) * 64;

    const _Float16* Ap = (is_g ? Xf16 : Hf16) + (size_t)brow * 1024;
    const _Float16* Bp = is_g ? WiT + (size_t)bcol * 1024
                              : WhTh + (size_t)(bcol - 3072) * 1024;

    f32x4 acc[4][4];
#pragma unroll
    for (int i = 0; i < 4; ++i)
#pragma unroll
      for (int j = 0; j < 4; ++j) acc[i][j] = f32x4{0.f, 0.f, 0.f, 0.f};

    kloop<false, 128, 128>(Ap, Bp, nullptr, lds, tid, acc);

    // D(row,col): col = lane&15, row = (lane>>4)*4 + j
    if (is_g) {                       // g (fp16) + BN column partial sums
      float s[4] = {0.f, 0.f, 0.f, 0.f}, q[4] = {0.f, 0.f, 0.f, 0.f};
#pragma unroll
      for (int m = 0; m < 4; ++m) {
        int row = brow + wrow + m * 16 + (lane >> 4) * 4;
#pragma unroll
        for (int n = 0; n < 4; ++n) {
          int gcol = bcol + wcol + n * 16 + (lane & 15);
#pragma unroll
          for (int j = 0; j < 4; ++j) {
            float v = acc[m][n][j];
            g16[(size_t)(row + j) * 3072 + gcol] = (_Float16)v;
            s[n] += v;
            q[n] += v * v;
          }
        }
      }
#pragma unroll
      for (int n = 0; n < 4; ++n) {
        float sv = s[n], qv = q[n];
        sv += __shfl_xor(sv, 16); sv += __shfl_xor(sv, 32);
        qv += __shfl_xor(qv, 16); qv += __shfl_xor(qv, 32);
        if (lane < 16) {
          int prow = by * 2 + (wid >> 1);            // 64 partial rows
          int pcol = bcol + wcol + n * 16 + lane;
          psum[(size_t)prow * 3072 + pcol] = sv;
          psq [(size_t)prow * 3072 + pcol] = qv;
        }
      }
    } else {                          // raw gh_u (fp16), ghbuf stride 2048
      int gh0 = bcol - 3072;
#pragma unroll
      for (int m = 0; m < 4; ++m) {
        int row = brow + wrow + m * 16 + (lane >> 4) * 4;
#pragma unroll
        for (int n = 0; n < 4; ++n) {
          int gcol = gh0 + wcol + n * 16 + (lane & 15);
#pragma unroll
          for (int j = 0; j < 4; ++j)
            ghbuf[(size_t)(row + j) * 2048 + gcol] = (_Float16)acc[m][n][j];
        }
      }
    }
  } else {
    // ---- phase 2: 128x64, 2-pass (B hi+lo) over gh_r
    int b2 = bid - 1024;
    int w  = (b2 & 7) * 64 + (b2 >> 3);
    int bx = w >> 5, by = w & 31;
    const int brow = by * 128;
    const int bcol = bx * 64;                        // 0..1023 within r
    const int wrow = (wid >> 1) * 64;
    const int wcol = (wid & 1) * 32;

    const _Float16* Ap = Hf16 + (size_t)brow * 1024;
    const _Float16* Bp = WhTh + (size_t)(1024 + bcol) * 1024;
    const _Float16* Bl = WhTl + (size_t)(1024 + bcol) * 1024;

    f32x4 acc[4][2];
#pragma unroll
    for (int i = 0; i < 4; ++i)
#pragma unroll
      for (int j = 0; j < 2; ++j) acc[i][j] = f32x4{0.f, 0.f, 0.f, 0.f};

    kloop<true, 128, 64>(Ap, Bp, Bl, lds, tid, acc);

#pragma unroll
    for (int m = 0; m < 4; ++m) {
      int row = brow + wrow + m * 16 + (lane >> 4) * 4;
#pragma unroll
      for (int n = 0; n < 2; ++n) {
        int gcol = 1024 + bcol + wcol + n * 16 + (lane & 15);   // gh_r cols
#pragma unroll
        for (int j = 0; j < 4; ++j)
          ghbuf[(size_t)(row + j) * 2048 + gcol] = (_Float16)acc[m][n][j];
      }
    }
  }
}

// ---- GEMM3: ch = rx @ wh_c; epilogue computes u (from raw gh_u) and hy
__global__ __launch_bounds__(256, 4) void gemm_last(
    const _Float16* __restrict__ RXf16, const _Float16* __restrict__ Bc,
    const _Float16* __restrict__ g16, const _Float16* __restrict__ ghbuf,
    const _Float16* __restrict__ Hf16, const float* __restrict__ scale,
    const float* __restrict__ shift, float* __restrict__ out) {
  __shared__ _Float16 lds[64 * 64 + 64 * 64];        // 16 KiB

  const int tid  = threadIdx.x;
  const int lane = tid & 63;
  const int wid  = tid >> 6;

  int flat = blockIdx.y * gridDim.x + blockIdx.x;    // gridDim = (16,64)
  int cpx  = gridDim.x >> 3;                         // 2
  int xcd  = flat & 7, idx = flat >> 3;
  int bx   = xcd * cpx + idx / gridDim.y;
  int by   = idx % gridDim.y;

  const int brow = by * 64;
  const int bcol = bx * 64;                          // 0..1023
  const int wrow = (wid >> 1) * 32;
  const int wcol = (wid & 1) * 32;

  f32x4 acc[2][2];
#pragma unroll
  for (int i = 0; i < 2; ++i)
#pragma unroll
    for (int j = 0; j < 2; ++j) acc[i][j] = f32x4{0.f, 0.f, 0.f, 0.f};

  kloop<false, 64, 64>(RXf16 + (size_t)brow * 1024, Bc + (size_t)bcol * 1024,
                       nullptr, lds, tid, acc);

#pragma unroll
  for (int m = 0; m < 2; ++m) {
    int row0 = brow + wrow + m * 16 + (lane >> 4) * 4;
#pragma unroll
    for (int n = 0; n < 2; ++n) {
      int lcol = bcol + wcol + n * 16 + (lane & 15);
      float sc_u = scale[lcol],        sf_u = shift[lcol];
      float sc_c = scale[2048 + lcol], sf_c = shift[2048 + lcol];
#pragma unroll
      for (int j = 0; j < 4; ++j) {
        int row = row0 + j;
        float gu = (float)g16[(size_t)row * 3072 + lcol];
        float hu = (float)ghbuf[(size_t)row * 2048 + lcol];
        float u  = sigm(gu * sc_u + sf_u + hu);
        float gc = (float)g16[(size_t)row * 3072 + 2048 + lcol];
        float c  = tanh_sat(gc * sc_c + sf_c + acc[m][n][j]);
        float x  = (float)Hf16[(size_t)row * 1024 + lcol];
        out[(size_t)row * 1024 + lcol] = x + u * (c - x);
      }
    }
  }
}

// --------------------------- BN final ---------------------------------------

__global__ void bn_final(const float* __restrict__ psum, const float* __restrict__ psq,
                         const float* __restrict__ gamma, const float* __restrict__ beta,
                         const float* __restrict__ bias, float* __restrict__ scale,
                         float* __restrict__ shift, int nparts, int Ncols, float invM) {
  int col = blockIdx.x * blockDim.x + threadIdx.x;
  if (col >= Ncols) return;
  float s = 0.f, q = 0.f;
  for (int i = 0; i < nparts; ++i) {
    s += psum[(size_t)i * Ncols + col];
    q += psq [(size_t)i * Ncols + col];
  }
  float m   = s * invM;
  float var = q * invM - m * m;
  float r   = rsqrtf(var + 1e-5f);
  float sc  = r * gamma[col];
  scale[col] = sc;
  shift[col] = beta[col] + bias[col] - m * sc;
}

// --------------------- rx = sigmoid(BN(g_r)+gh_r) * hx ----------------------

__global__ void rx_split(const _Float16* __restrict__ g16,
                         const _Float16* __restrict__ ghbuf,
                         const _Float16* __restrict__ Hf16,
                         const float* __restrict__ scale,
                         const float* __restrict__ shift,
                         _Float16* __restrict__ rx) {
  int idx = blockIdx.x * blockDim.x + threadIdx.x;   // 4096*256
  int row = idx >> 8;
  int cv  = idx & 255;
  half4 gr = ((const half4*)g16)[(size_t)row * 768 + 256 + cv];   // g cols 1024+
  half4 hr = ((const half4*)ghbuf)[(size_t)row * 512 + 256 + cv]; // gh cols 1024+
  half4 xv = ((const half4*)Hf16)[(size_t)row * 256 + cv];
  int col = 1024 + cv * 4;
  f4 sr = *(const f4*)&scale[col];
  f4 fr = *(const f4*)&shift[col];
  half4 o;
#pragma unroll
  for (int j = 0; j < 4; ++j) {
    float r = sigm((float)gr[j] * sr[j] + fr[j] + (float)hr[j]);
    o[j] = (_Float16)(r * (float)xv[j]);
  }
  ((half4*)rx)[(size_t)row * 256 + cv] = o;
}

// ------------------------------ launch ---------------------------------------

extern "C" void kernel_launch(void* const* d_in, const int* in_sizes, int n_in,
                              void* d_out, int out_size, void* d_ws, size_t ws_size,
                              hipStream_t stream) {
  const float* input = (const float*)d_in[0];   // 4096x1024
  const float* hx    = (const float*)d_in[1];   // 4096x1024
  const float* wi    = (const float*)d_in[2];   // 1024x3072
  const float* wh    = (const float*)d_in[3];   // 1024x3072
  const float* bias  = (const float*)d_in[4];   // 3072
  const float* gamma = (const float*)d_in[5];   // 3072
  const float* beta  = (const float*)d_in[6];   // 3072
  float* out = (float*)d_out;

  const int B = 4096, N3 = 3072;

  char* ws = (char*)d_ws;
  _Float16* g16   = (_Float16*)(ws);               // 24 MiB [4096][3072]
  _Float16* ghbuf = (_Float16*)(ws + 25165824);    // 16 MiB [4096][2048] raw
  _Float16* Xf16  = (_Float16*)(ws + 41943040);    // 8 MiB
  _Float16* Hf16  = (_Float16*)(ws + 50331648);    // 8 MiB
  _Float16* RXf16 = (_Float16*)(ws + 58720256);    // 8 MiB
  _Float16* WiT   = (_Float16*)(ws + 67108864);    // 6 MiB
  _Float16* WhTh  = (_Float16*)(ws + 73400320);    // 6 MiB
  _Float16* WhTl  = (_Float16*)(ws + 79691776);    // 6 MiB (r-cols only)
  float*    psum  = (float*)   (ws + 85983232);    // 768 KiB [64][3072]
  float*    psq   = (float*)   (ws + 86769664);    // 768 KiB
  float*    scale = (float*)   (ws + 87556096);    // 12 KiB
  float*    shift = (float*)   (ws + 87568384);    // 12 KiB

  // ---- prep: converts + transposes, one dispatch
  prep_all<<<8192 + 6144, 256, 0, stream>>>(input, hx, wi, wh,
                                            Xf16, Hf16, WiT, WhTh, WhTl);

  // ---- MEGA GEMM: [g | gh_u] 128x128 1-pass + gh_r 128x64 2-pass
  gemm_mega<<<1536, 256, 0, stream>>>(
      Xf16, Hf16, WiT, WhTh, WhTl, g16, ghbuf, psum, psq);

  // ---- BN fold
  bn_final<<<12, 256, 0, stream>>>(psum, psq, gamma, beta, bias,
                                   scale, shift, 64, N3, 1.f / (float)B);

  // ---- rx = sigmoid(BN(g_r) + gh_r) * hx
  rx_split<<<4096, 256, 0, stream>>>(g16, ghbuf, Hf16, scale, shift, RXf16);

  // ---- GEMM3 + fused u/c/hy epilogue
  gemm_last<<<dim3(16, 64), 256, 0, stream>>>(
      RXf16, WhTh + (size_t)2048 * 1024, g16, ghbuf, Hf16, scale, shift, out);
}